// Round 1
// baseline (203.222 us; speedup 1.0000x reference)
//
#include <hip/hip_runtime.h>
#include <math.h>

// Problem constants (from reference)
#define BATCH 128
#define CH 4
#define LEN 1000
#define NPWM 512
#define KSZ 19
#define NPOS 982          // LEN - KSZ + 1
#define CK 76             // CH * KSZ
#define LPAD 1024         // padded x row in LDS

#define FT 64             // pwms per block
#define CHUNKS 4          // position chunks per block
#define PBLK 8            // positions per register block
#define NBLK 31           // register blocks per chunk (31*8=248; 4*248=992 >= 982)

__global__ __launch_bounds__(256)
void pwm_scan_kernel(const float* __restrict__ x,
                     const float* __restrict__ w,
                     float* __restrict__ out)
{
    __shared__ float xs[CH][LPAD];
    __shared__ float red[CHUNKS][FT];

    const int tid   = threadIdx.x;
    const int b     = blockIdx.x;        // batch
    const int ftile = blockIdx.y;        // pwm tile
    const int fl    = tid & 63;          // pwm within tile (lane)
    const int chunk = tid >> 6;          // position chunk (== wave id)
    const int f     = ftile * FT + fl;

    // ---- stage x[b] into LDS (vectorized, coalesced) ----
    #pragma unroll
    for (int c = 0; c < CH; ++c) {
        const float4* src = (const float4*)(x + (size_t)b * CH * LEN + c * LEN);
        float4* dst = (float4*)(&xs[c][0]);
        for (int i = tid; i < LEN / 4; i += 256) dst[i] = src[i];
    }
    // zero the pad so OOB window reads are benign
    if (tid < CH * (LPAD - LEN)) {
        int c = tid / (LPAD - LEN);
        int j = tid - c * (LPAD - LEN);
        xs[c][LEN + j] = 0.0f;
    }

    // ---- load this thread's PWM into registers (76 floats = 19 x float4) ----
    float wr[CK];
    {
        const float4* wg = (const float4*)(w + (size_t)f * CK);
        #pragma unroll
        for (int i = 0; i < CK / 4; ++i) {
            float4 v = wg[i];
            wr[4*i+0] = v.x; wr[4*i+1] = v.y; wr[4*i+2] = v.z; wr[4*i+3] = v.w;
        }
    }
    __syncthreads();

    // ---- main scan: this chunk's positions, both strands ----
    float m = -INFINITY;
    const int p_base = chunk * (NBLK * PBLK);

    for (int blk = 0; blk < NBLK; ++blk) {
        const int p0 = p_base + blk * PBLK;

        float sf[PBLK], sr[PBLK];
        #pragma unroll
        for (int j = 0; j < PBLK; ++j) { sf[j] = 0.0f; sr[j] = 0.0f; }

        #pragma unroll
        for (int c = 0; c < CH; ++c) {
            // window x[c][p0 .. p0+27] (need up to p0+25); broadcast LDS reads
            float win[28];
            const float4* wp = (const float4*)(&xs[c][p0]);
            #pragma unroll
            for (int i = 0; i < 7; ++i) {
                float4 v = wp[i];
                win[4*i+0] = v.x; win[4*i+1] = v.y; win[4*i+2] = v.z; win[4*i+3] = v.w;
            }
            #pragma unroll
            for (int k = 0; k < KSZ; ++k) {
                const float wf = wr[c * KSZ + k];                       // forward
                const float wv = wr[(3 - c) * KSZ + (KSZ - 1 - k)];     // rev-comp
                #pragma unroll
                for (int j = 0; j < PBLK; ++j) {
                    sf[j] = fmaf(win[k + j], wf, sf[j]);
                    sr[j] = fmaf(win[k + j], wv, sr[j]);
                }
            }
        }

        #pragma unroll
        for (int j = 0; j < PBLK; ++j) {
            if (p0 + j < NPOS) {
                m = fmaxf(m, sf[j]);
                m = fmaxf(m, sr[j]);
            }
        }
    }

    // ---- reduce across the 4 chunks ----
    red[chunk][fl] = m;
    __syncthreads();
    if (tid < FT) {
        float r = red[0][tid];
        r = fmaxf(r, red[1][tid]);
        r = fmaxf(r, red[2][tid]);
        r = fmaxf(r, red[3][tid]);
        out[(size_t)b * NPWM + ftile * FT + tid] = r;
    }
}

extern "C" void kernel_launch(void* const* d_in, const int* in_sizes, int n_in,
                              void* d_out, int out_size, void* d_ws, size_t ws_size,
                              hipStream_t stream)
{
    const float* x = (const float*)d_in[0];   // (128, 4, 1000)
    const float* w = (const float*)d_in[1];   // (512, 4, 19)
    float* out = (float*)d_out;               // (128, 512)

    dim3 grid(BATCH, NPWM / FT);
    pwm_scan_kernel<<<grid, 256, 0, stream>>>(x, w, out);
}

// Round 2
// 54.486 us; speedup vs baseline: 3.7298x; 3.7298x over previous
//
#include <hip/hip_runtime.h>
#include <math.h>

#define BATCH 128
#define CH 4
#define LEN 1000
#define NPWM 512
#define KSZ 19
#define NPOS 982
#define NEXT 1024     // 2*NPWM (fwd + revcomp interleaved: f_ext = 2*f + strand)
#define KSLOT 96      // kk padded 19->24, slot = kk*4 + c

typedef __bf16 bf16x8 __attribute__((ext_vector_type(8)));
typedef float  f32x4  __attribute__((ext_vector_type(4)));

#define MFMA(a, b, c) __builtin_amdgcn_mfma_f32_16x16x32_bf16(a, b, c, 0, 0, 0)

// ---- prepack W: (512,4,19) fp32 -> (1024,96) bf16 hi/lo, zeros at pad slots ----
__global__ __launch_bounds__(256)
void prepack_w(const float* __restrict__ w, __bf16* __restrict__ whi, __bf16* __restrict__ wlo)
{
    int idx = blockIdx.x * 256 + threadIdx.x;
    if (idx >= NEXT * KSLOT) return;
    int fe = idx / KSLOT;
    int t  = idx - fe * KSLOT;
    int kk = t >> 2;
    int c  = t & 3;
    int f      = fe >> 1;
    int strand = fe & 1;
    float v = 0.0f;
    if (kk < KSZ)
        v = strand ? w[f*76 + (3-c)*19 + (18-kk)]   // reverse-complement
                   : w[f*76 + c*19 + kk];
    __bf16 h = (__bf16)v;
    whi[idx] = h;
    wlo[idx] = (__bf16)(v - (float)h);
}

// ---- main: im2col bf16-split MFMA GEMM + fused position-max ----
// block = 256 thr (4 waves), covers batch b x 128 f_ext (= 64 output filters), all positions
__global__ __launch_bounds__(256)
void pwm_mfma(const float* __restrict__ x,
              const __bf16* __restrict__ whi,
              const __bf16* __restrict__ wlo,
              float* __restrict__ out)
{
    __shared__ __align__(16) __bf16 xt0[4096]; // hi,  [pos][c], pos 0..1023 (tail zeroed)
    __shared__ __align__(16) __bf16 xt1[4096]; // hi, shifted +1 pos (odd-lane alignment)
    __shared__ __align__(16) __bf16 xt2[4096]; // lo
    __shared__ __align__(16) __bf16 xt3[4096]; // lo, shifted
    __shared__ float red[128];

    const int tid   = threadIdx.x;
    const int b     = blockIdx.x;
    const int ftile = blockIdx.y;   // 0..7
    const int lane  = tid & 63;
    const int wave  = tid >> 6;

    // stage x[b] -> bf16 hi/lo, position-major [pos][channel]
    for (int i = tid; i < 1024; i += 256) {
        #pragma unroll
        for (int c = 0; c < 4; ++c) {
            float v = (i < LEN) ? x[(size_t)b*4000 + c*1000 + i] : 0.0f;
            __bf16 h = (__bf16)v;
            xt0[i*4+c] = h;
            xt2[i*4+c] = (__bf16)(v - (float)h);
        }
    }
    __syncthreads();
    { // shifted copies (pos+1), zero tail
        const unsigned long long* s0 = (const unsigned long long*)xt0;
        const unsigned long long* s2 = (const unsigned long long*)xt2;
        unsigned long long* d1 = (unsigned long long*)xt1;
        unsigned long long* d3 = (unsigned long long*)xt3;
        for (int i = tid; i < 1024; i += 256) {
            d1[i] = (i < 1023) ? s0[i+1] : 0ull;
            d3[i] = (i < 1023) ? s2[i+1] : 0ull;
        }
    }

    // A fragments (W) -> registers; lane holds W[f= f0+fg*16+row][k = s*32 + g*8 + j]
    const int row = lane & 15;
    const int g   = lane >> 4;
    bf16x8 wah[2][3], wal[2][3];
    {
        const int f0 = ftile*128 + wave*32;
        #pragma unroll
        for (int fg = 0; fg < 2; ++fg) {
            const __bf16* ph = whi + (size_t)(f0 + fg*16 + row)*KSLOT + g*8;
            const __bf16* pl = wlo + (size_t)(f0 + fg*16 + row)*KSLOT + g*8;
            #pragma unroll
            for (int s = 0; s < 3; ++s) {
                wah[fg][s] = *(const bf16x8*)(ph + s*32);
                wal[fg][s] = *(const bf16x8*)(pl + s*32);
            }
        }
    }
    __syncthreads();

    // per-lane LDS base: pos = it*32 + 16P + 8s + lp; parity(pos) = row&1 (loop-invariant)
    const int lp = row + 2*g;
    const __bf16* bhi = (row & 1) ? xt1 : xt0;
    const __bf16* blo = (row & 1) ? xt3 : xt2;
    const int eoff = lp*4 - ((row & 1) ? 4 : 0);   // element offset; keeps reads 16B-aligned

    float m[2][4];
    #pragma unroll
    for (int fg = 0; fg < 2; ++fg)
        #pragma unroll
        for (int r = 0; r < 4; ++r) m[fg][r] = -INFINITY;

    for (int it = 0; it < 31; ++it) {
        f32x4 acc00 = {0,0,0,0}, acc01 = {0,0,0,0}, acc10 = {0,0,0,0}, acc11 = {0,0,0,0};
        const int ibase = it*128 + eoff;
        #pragma unroll
        for (int s = 0; s < 3; ++s) {
            bf16x8 bh0 = *(const bf16x8*)(bhi + ibase + s*32);
            bf16x8 bl0 = *(const bf16x8*)(blo + ibase + s*32);
            bf16x8 bh1 = *(const bf16x8*)(bhi + ibase + 64 + s*32);
            bf16x8 bl1 = *(const bf16x8*)(blo + ibase + 64 + s*32);
            acc00 = MFMA(wah[0][s], bh0, acc00);
            acc00 = MFMA(wah[0][s], bl0, acc00);
            acc00 = MFMA(wal[0][s], bh0, acc00);
            acc10 = MFMA(wah[1][s], bh0, acc10);
            acc10 = MFMA(wah[1][s], bl0, acc10);
            acc10 = MFMA(wal[1][s], bh0, acc10);
            acc01 = MFMA(wah[0][s], bh1, acc01);
            acc01 = MFMA(wah[0][s], bl1, acc01);
            acc01 = MFMA(wal[0][s], bh1, acc01);
            acc11 = MFMA(wah[1][s], bh1, acc11);
            acc11 = MFMA(wah[1][s], bl1, acc11);
            acc11 = MFMA(wal[1][s], bh1, acc11);
        }
        if (it == 30 && row >= 6) {   // mask positions >= 982 (cols of P=1 tile)
            #pragma unroll
            for (int r = 0; r < 4; ++r) { acc01[r] = -INFINITY; acc11[r] = -INFINITY; }
        }
        #pragma unroll
        for (int r = 0; r < 4; ++r) {
            m[0][r] = fmaxf(m[0][r], fmaxf(acc00[r], acc01[r]));
            m[1][r] = fmaxf(m[1][r], fmaxf(acc10[r], acc11[r]));
        }
    }

    // reduce over the 16 position-columns (lanes 0..15 of each 16-group)
    #pragma unroll
    for (int off = 1; off < 16; off <<= 1)
        #pragma unroll
        for (int fg = 0; fg < 2; ++fg)
            #pragma unroll
            for (int r = 0; r < 4; ++r)
                m[fg][r] = fmaxf(m[fg][r], __shfl_xor(m[fg][r], off, 64));

    if (row == 0) {
        #pragma unroll
        for (int fg = 0; fg < 2; ++fg)
            #pragma unroll
            for (int r = 0; r < 4; ++r)
                red[wave*32 + fg*16 + g*4 + r] = m[fg][r];
    }
    __syncthreads();
    if (tid < 64)   // combine fwd/rc strand pair (f_ext = 2f, 2f+1)
        out[(size_t)b*NPWM + ftile*64 + tid] = fmaxf(red[2*tid], red[2*tid+1]);
}

extern "C" void kernel_launch(void* const* d_in, const int* in_sizes, int n_in,
                              void* d_out, int out_size, void* d_ws, size_t ws_size,
                              hipStream_t stream)
{
    const float* x = (const float*)d_in[0];   // (128, 4, 1000)
    const float* w = (const float*)d_in[1];   // (512, 4, 19)
    float* out = (float*)d_out;               // (128, 512)

    __bf16* whi = (__bf16*)d_ws;              // 1024*96 bf16
    __bf16* wlo = whi + NEXT*KSLOT;           // + 192KB

    prepack_w<<<dim3((NEXT*KSLOT + 255)/256), 256, 0, stream>>>(w, whi, wlo);
    pwm_mfma<<<dim3(BATCH, 8), 256, 0, stream>>>(x, whi, wlo, out);
}